// Round 14
// baseline (29792.007 us; speedup 1.0000x reference)
//
#include <hip/hip_runtime.h>
#include <math.h>

#define T_STEPS 400
#define BATCH   32
#define HID     1024
#define MROWS   (T_STEPS * BATCH)   // 12800
#define NCLS    3500
#define NG      8                    // batch groups
#define BPG     4                    // batch rows per group
#define CPG2    64                   // blocks (column slices) per group
#define JS2     16                   // columns per block
#define EPS     1e-6f
#define SLOTP   8                    // ints per progress slot (32B padding)

typedef __attribute__((ext_vector_type(8))) short short8v;   // 8 bf16 (4 VGPR)
typedef __attribute__((ext_vector_type(4))) float f32x4;

__device__ __forceinline__ unsigned short bf16_rne(float x) {
  unsigned u = __builtin_bit_cast(unsigned, x);
  unsigned r = u + 0x7FFFu + ((u >> 16) & 1u);
  return (unsigned short)(r >> 16);
}

// stage a 128x32 fp32 tile into hi/lo bf16 LDS tiles (chunk-XOR swizzled).
__device__ __forceinline__ void stage_tile(
    const float* __restrict__ src, int rowlim, int row0, int ld,
    int k0, int K, unsigned short* hi, unsigned short* lo, int tid) {
  #pragma unroll
  for (int it = 0; it < 2; ++it) {
    const int task = tid + 256 * it;          // 512 tasks: 128 rows x 4 chunks
    const int r = task >> 2, q = task & 3;
    const int gr = row0 + r;
    const bool rok = gr < rowlim;
    const float* p = src + (size_t)gr * ld + k0 + q * 8;
    float x[8];
    if (rok && (k0 + 32 <= K)) {
      float4 v0 = *(const float4*)p;
      float4 v1 = *(const float4*)(p + 4);
      x[0] = v0.x; x[1] = v0.y; x[2] = v0.z; x[3] = v0.w;
      x[4] = v1.x; x[5] = v1.y; x[6] = v1.z; x[7] = v1.w;
    } else {
      #pragma unroll
      for (int j = 0; j < 8; ++j)
        x[j] = (rok && (k0 + q * 8 + j) < K) ? p[j] : 0.f;
    }
    unsigned hp[4], lp[4];
    #pragma unroll
    for (int j = 0; j < 4; ++j) {
      unsigned short h0 = bf16_rne(x[2 * j]), h1 = bf16_rne(x[2 * j + 1]);
      float f0 = __builtin_bit_cast(float, (unsigned)h0 << 16);
      float f1 = __builtin_bit_cast(float, (unsigned)h1 << 16);
      unsigned short l0 = bf16_rne(x[2 * j] - f0), l1 = bf16_rne(x[2 * j + 1] - f1);
      hp[j] = (unsigned)h0 | ((unsigned)h1 << 16);
      lp[j] = (unsigned)l0 | ((unsigned)l1 << 16);
    }
    const int idx = (r * 4 + (q ^ (r & 3))) * 8;   // 16B-chunk swizzle
    *(uint4*)&hi[idx] = make_uint4(hp[0], hp[1], hp[2], hp[3]);
    *(uint4*)&lo[idx] = make_uint4(lp[0], lp[1], lp[2], lp[3]);
  }
}

// ---------------- MFMA GEMM: C[M][N] = A[M][K] @ W[N][K]^T + bias[N] ----------------
template <int NPASS>
__global__ __launch_bounds__(256) void gemm_mfma(
    const float* __restrict__ A, const float* __restrict__ W,
    const float* __restrict__ bias, float* __restrict__ C,
    int M, int N, int K) {
  __shared__ unsigned short Ah[128 * 32], Al[128 * 32];
  __shared__ unsigned short Bh[128 * 32], Bl[128 * 32];
  const int tid = threadIdx.x;
  const int m0 = blockIdx.y * 128, n0 = blockIdx.x * 128;
  const int w = tid >> 6, lane = tid & 63;
  const int rlow = lane & 15, ksel = lane >> 4;

  f32x4 acc[8][2];
  #pragma unroll
  for (int i = 0; i < 8; ++i) {
    acc[i][0] = (f32x4)(0.f);
    acc[i][1] = (f32x4)(0.f);
  }

  for (int k0 = 0; k0 < K; k0 += 32) {
    __syncthreads();
    stage_tile(A, M, m0, K, k0, K, Ah, Al, tid);
    stage_tile(W, N, n0, K, k0, K, Bh, Bl, tid);
    __syncthreads();

    short8v wh[2], wl[2];
    #pragma unroll
    for (int nf = 0; nf < 2; ++nf) {
      const int rn = w * 32 + nf * 16 + rlow;
      const int idx = (rn * 4 + (ksel ^ (rn & 3))) * 8;
      wh[nf] = *(const short8v*)&Bh[idx];
      if (NPASS == 3) wl[nf] = *(const short8v*)&Bl[idx];
    }
    #pragma unroll
    for (int i = 0; i < 8; ++i) {
      const int ra = i * 16 + rlow;
      const int idx = (ra * 4 + (ksel ^ (ra & 3))) * 8;
      short8v ah = *(const short8v*)&Ah[idx];
      if (NPASS == 3) {
        short8v al = *(const short8v*)&Al[idx];
        acc[i][0] = __builtin_amdgcn_mfma_f32_16x16x32_bf16(ah, wh[0], acc[i][0], 0, 0, 0);
        acc[i][0] = __builtin_amdgcn_mfma_f32_16x16x32_bf16(al, wh[0], acc[i][0], 0, 0, 0);
        acc[i][0] = __builtin_amdgcn_mfma_f32_16x16x32_bf16(ah, wl[0], acc[i][0], 0, 0, 0);
        acc[i][1] = __builtin_amdgcn_mfma_f32_16x16x32_bf16(ah, wh[1], acc[i][1], 0, 0, 0);
        acc[i][1] = __builtin_amdgcn_mfma_f32_16x16x32_bf16(al, wh[1], acc[i][1], 0, 0, 0);
        acc[i][1] = __builtin_amdgcn_mfma_f32_16x16x32_bf16(ah, wl[1], acc[i][1], 0, 0, 0);
      } else {
        acc[i][0] = __builtin_amdgcn_mfma_f32_16x16x32_bf16(ah, wh[0], acc[i][0], 0, 0, 0);
        acc[i][1] = __builtin_amdgcn_mfma_f32_16x16x32_bf16(ah, wh[1], acc[i][1], 0, 0, 0);
      }
    }
  }

  int col[2]; float bb[2]; bool cok[2];
  #pragma unroll
  for (int nf = 0; nf < 2; ++nf) {
    col[nf] = n0 + w * 32 + nf * 16 + rlow;
    cok[nf] = col[nf] < N;
    bb[nf] = cok[nf] ? bias[col[nf]] : 0.f;
  }
  #pragma unroll
  for (int i = 0; i < 8; ++i) {
    const int row = m0 + i * 16 + ksel * 4;
    #pragma unroll
    for (int nf = 0; nf < 2; ++nf) {
      if (cok[nf]) {
        float* cp = C + (size_t)row * N + col[nf];
        cp[0 * N] = acc[i][nf][0] + bb[nf];
        cp[1 * N] = acc[i][nf][1] + bb[nf];
        cp[2 * N] = acc[i][nf][2] + bb[nf];
        cp[3 * N] = acc[i][nf][3] + bb[nf];
      }
    }
  }
}

// ---------------- fused 2-layer wavefront scan: 512 blocks x 256 thr, 16-col slices ----
// g = blk>>6 (contiguous groups -> deadlock-free even at 1 block/CU: groups independent).
// Per tick k: layer-a does t=k (k<T), layer-b does t=k-1 (k>=1); ONE sync round per tick.
// Weights: 3 x 64 fp32/thread = 192 VGPR; pacc[2][8] two-pass keeps peak ~245 <= 256
// (the budget launch_bounds(256,1) is proven to reach - round 9 measured VGPR=256).
__global__ __launch_bounds__(256, 1) void scan_pair(
    const float* __restrict__ wx,       // a-layer wx [T][32][1024]
    const float* __restrict__ ua_w,     // Uh layer a [1024][1024] (row=out col)
    const float* __restrict__ ub_w,     // Uh layer b
    const float* __restrict__ wb_w,     // Wx layer b
    const float* __restrict__ wb_bias,  // Wx bias layer b [1024]
    float* __restrict__ h_all,          // b-layer h out
    float* __restrict__ pre_prev,       // a-layer skip source (ignored if skip)
    float* __restrict__ pre_out,        // b-layer pre out
    float* __restrict__ a_pub,          // [2 par][NG][2 layer][BPG][HID]
    int* __restrict__ prog,             // [NG][CPG2][SLOTP]
    const float* __restrict__ g_a, const float* __restrict__ be_a,
    const float* __restrict__ g_b, const float* __restrict__ be_b,
    int skip_sub) {
  const int tid  = threadIdx.x;
  const int g    = blockIdx.x >> 6;
  const int c    = blockIdx.x & 63;
  const int lane = tid & 63;
  const int wv   = tid >> 6;          // wave 0..3
  const int jw   = tid & 1;
  const int ks   = tid >> 1;          // 0..127
  const int col0 = c * JS2 + jw * 8;

  int* prog_g = prog + (size_t)g * CPG2 * SLOTP;

  __shared__ float h_a_lds[HID * BPG];      // [k*4+b], 16KB
  __shared__ float h_b_lds[HID * BPG];      // 16KB
  __shared__ float a2_lds[2 * BPG * HID];   // [row*1024+k], rows 0-3 = a, 4-7 = b; 32KB
  __shared__ float partial_a[4][BPG][JS2];  // 1KB
  __shared__ float partial_b[4][BPG][JS2];  // 1KB
  __shared__ float stats_lds[8][2];

  // ---- prologue: weight slices into registers (one-time scattered loads) ----
  float4 ua0[8], ua1[8], ub0[8], ub1[8], wb0[8], wb1[8];
  #pragma unroll
  for (int i = 0; i < 8; ++i) {
    const int kk = ks + 128 * i;
    float a0[8], b0[8], w0[8];
    #pragma unroll
    for (int q = 0; q < 8; ++q) {
      const size_t off = (size_t)(col0 + q) * HID + kk;   // W[j][k]
      a0[q] = ua_w[off];
      b0[q] = ub_w[off];
      w0[q] = wb_w[off];
    }
    ua0[i] = make_float4(a0[0], a0[1], a0[2], a0[3]);
    ua1[i] = make_float4(a0[4], a0[5], a0[6], a0[7]);
    ub0[i] = make_float4(b0[0], b0[1], b0[2], b0[3]);
    ub1[i] = make_float4(b0[4], b0[5], b0[6], b0[7]);
    wb0[i] = make_float4(w0[0], w0[1], w0[2], w0[3]);
    wb1[i] = make_float4(w0[4], w0[5], w0[6], w0[7]);
  }
  // LN params (both layers) for rows kk = tid + 256*j
  float ga[4], ba[4], gb[4], bbq[4];
  #pragma unroll
  for (int j = 0; j < 4; ++j) {
    const int kk = tid + 256 * j;
    ga[j] = g_a[kk]; ba[j] = be_a[kk];
    gb[j] = g_b[kk]; bbq[j] = be_b[kk];
  }
  float biasb = 0.f, pre_a_reg = 0.f;
  if (tid < 64) biasb = wb_bias[c * JS2 + (tid & 15)];
  __syncthreads();

  for (int k = 0; k <= T_STEPS; ++k) {
    const int par = k & 1;
    float* pbase = a_pub + ((size_t)par * NG + g) * (2 * BPG * HID);
    const bool doA = (k < T_STEPS);
    const bool doB = (k >= 1);

    // a-layer wx/pre loads (issued early, consumed at publish)
    float wxa_r = 0.f, prev_r = 0.f;
    size_t gia = 0;
    if (doA && tid < 64) {
      const int b = tid >> 4, j = tid & 15;
      gia = ((size_t)k * BATCH + g * BPG + b) * HID + c * JS2 + j;
      wxa_r = wx[gia];
      if (!skip_sub)
        prev_r = __hip_atomic_load(&pre_prev[gia], __ATOMIC_RELAXED, __HIP_MEMORY_SCOPE_AGENT);
    }

    // ---- a-layer Ua matvec (rows 2 at a time: pacc[2][8]) ----
    if (doA && k > 0) {
      #pragma unroll
      for (int p = 0; p < 2; ++p) {
        float pacc[2][8];
        #pragma unroll
        for (int r = 0; r < 2; ++r)
          #pragma unroll
          for (int q = 0; q < 8; ++q) pacc[r][q] = 0.f;
        #pragma unroll
        for (int i = 0; i < 8; ++i) {
          float4 h4 = *(const float4*)&h_a_lds[(ks + 128 * i) * 4];
          const float* hp = (const float*)&h4;
          #pragma unroll
          for (int r = 0; r < 2; ++r) {
            float hv = hp[2 * p + r];
            pacc[r][0] += hv * ua0[i].x; pacc[r][1] += hv * ua0[i].y;
            pacc[r][2] += hv * ua0[i].z; pacc[r][3] += hv * ua0[i].w;
            pacc[r][4] += hv * ua1[i].x; pacc[r][5] += hv * ua1[i].y;
            pacc[r][6] += hv * ua1[i].z; pacc[r][7] += hv * ua1[i].w;
          }
        }
        #pragma unroll
        for (int r = 0; r < 2; ++r)
          #pragma unroll
          for (int q = 0; q < 8; ++q) {
            float v = pacc[r][q];
            v += __shfl_xor(v, 2); v += __shfl_xor(v, 4); v += __shfl_xor(v, 8);
            v += __shfl_xor(v, 16); v += __shfl_xor(v, 32);
            pacc[r][q] = v;
          }
        if (lane < 2) {
          #pragma unroll
          for (int r = 0; r < 2; ++r) {
            *(float4*)&partial_a[wv][2 * p + r][lane * 8] =
                make_float4(pacc[r][0], pacc[r][1], pacc[r][2], pacc[r][3]);
            *(float4*)&partial_a[wv][2 * p + r][lane * 8 + 4] =
                make_float4(pacc[r][4], pacc[r][5], pacc[r][6], pacc[r][7]);
          }
        }
      }
    }

    // ---- b-layer Wb@h_a (+ Ub@h_b if k>=2) ----
    if (doB) {
      #pragma unroll
      for (int p = 0; p < 2; ++p) {
        float pacc[2][8];
        #pragma unroll
        for (int r = 0; r < 2; ++r)
          #pragma unroll
          for (int q = 0; q < 8; ++q) pacc[r][q] = 0.f;
        #pragma unroll
        for (int i = 0; i < 8; ++i) {
          float4 ha = *(const float4*)&h_a_lds[(ks + 128 * i) * 4];
          const float* hap = (const float*)&ha;
          #pragma unroll
          for (int r = 0; r < 2; ++r) {
            float hv = hap[2 * p + r];
            pacc[r][0] += hv * wb0[i].x; pacc[r][1] += hv * wb0[i].y;
            pacc[r][2] += hv * wb0[i].z; pacc[r][3] += hv * wb0[i].w;
            pacc[r][4] += hv * wb1[i].x; pacc[r][5] += hv * wb1[i].y;
            pacc[r][6] += hv * wb1[i].z; pacc[r][7] += hv * wb1[i].w;
          }
          if (k >= 2) {
            float4 hb4 = *(const float4*)&h_b_lds[(ks + 128 * i) * 4];
            const float* hbp = (const float*)&hb4;
            #pragma unroll
            for (int r = 0; r < 2; ++r) {
              float hv = hbp[2 * p + r];
              pacc[r][0] += hv * ub0[i].x; pacc[r][1] += hv * ub0[i].y;
              pacc[r][2] += hv * ub0[i].z; pacc[r][3] += hv * ub0[i].w;
              pacc[r][4] += hv * ub1[i].x; pacc[r][5] += hv * ub1[i].y;
              pacc[r][6] += hv * ub1[i].z; pacc[r][7] += hv * ub1[i].w;
            }
          }
        }
        #pragma unroll
        for (int r = 0; r < 2; ++r)
          #pragma unroll
          for (int q = 0; q < 8; ++q) {
            float v = pacc[r][q];
            v += __shfl_xor(v, 2); v += __shfl_xor(v, 4); v += __shfl_xor(v, 8);
            v += __shfl_xor(v, 16); v += __shfl_xor(v, 32);
            pacc[r][q] = v;
          }
        if (lane < 2) {
          #pragma unroll
          for (int r = 0; r < 2; ++r) {
            *(float4*)&partial_b[wv][2 * p + r][lane * 8] =
                make_float4(pacc[r][0], pacc[r][1], pacc[r][2], pacc[r][3]);
            *(float4*)&partial_b[wv][2 * p + r][lane * 8 + 4] =
                make_float4(pacc[r][4], pacc[r][5], pacc[r][6], pacc[r][7]);
          }
        }
      }
    }
    __syncthreads();

    // ---- publish both layers (all publishers in wave 0 -> wave-level vmcnt drain) ----
    if (tid < 64) {
      const int b = tid >> 4, j = tid & 15;
      float at_a = 0.f;
      if (doA) {
        float red = 0.f;
        if (k > 0)
          red = partial_a[0][b][j] + partial_a[1][b][j]
              + partial_a[2][b][j] + partial_a[3][b][j];
        at_a = wxa_r + red;
        __hip_atomic_store(&pbase[(size_t)b * HID + c * JS2 + j], at_a - prev_r,
                           __ATOMIC_RELAXED, __HIP_MEMORY_SCOPE_AGENT);
      }
      if (doB) {
        float redb = partial_b[0][b][j] + partial_b[1][b][j]
                   + partial_b[2][b][j] + partial_b[3][b][j];
        float at_b = biasb + redb;
        const size_t gib = ((size_t)(k - 1) * BATCH + g * BPG + b) * HID + c * JS2 + j;
        __hip_atomic_store(&pre_out[gib], at_b,
                           __ATOMIC_RELAXED, __HIP_MEMORY_SCOPE_AGENT);
        __hip_atomic_store(&pbase[(size_t)(BPG * HID) + b * HID + c * JS2 + j],
                           at_b - pre_a_reg,
                           __ATOMIC_RELAXED, __HIP_MEMORY_SCOPE_AGENT);
      }
      if (doA) pre_a_reg = at_a;   // update AFTER b consumed previous-tick value
    }
    asm volatile("s_waitcnt vmcnt(0)" ::: "memory");
    if (tid == 0)
      __hip_atomic_store(&prog_g[c * SLOTP], k + 1,
                         __ATOMIC_RELAXED, __HIP_MEMORY_SCOPE_AGENT);
    // wave 0: 64 lanes <-> 64 slots
    if (wv == 0) {
      const int* p = &prog_g[lane * SLOTP];
      bool first = true;
      while (true) {
        int v = __hip_atomic_load(p, __ATOMIC_RELAXED, __HIP_MEMORY_SCOPE_AGENT);
        if (__all(v >= k + 1)) break;
        if (!first) __builtin_amdgcn_s_sleep(1);
        first = false;
      }
    }
    __syncthreads();

    // ---- fused readback + stats: wave wv owns rows wv (layer a) and wv+4 (layer b) ----
    {
      float s1a = 0.f, s2a = 0.f, s1b = 0.f, s2b = 0.f;
      #pragma unroll
      for (int i = 0; i < 16; ++i) {
        float va = __hip_atomic_load(&pbase[(size_t)wv * HID + i * 64 + lane],
                                     __ATOMIC_RELAXED, __HIP_MEMORY_SCOPE_AGENT);
        float vb = __hip_atomic_load(&pbase[(size_t)(4 + wv) * HID + i * 64 + lane],
                                     __ATOMIC_RELAXED, __HIP_MEMORY_SCOPE_AGENT);
        a2_lds[wv * HID + i * 64 + lane] = va;
        a2_lds[(4 + wv) * HID + i * 64 + lane] = vb;
        s1a += va; s2a += va * va;
        s1b += vb; s2b += vb * vb;
      }
      #pragma unroll
      for (int m = 1; m <= 32; m <<= 1) {
        s1a += __shfl_xor(s1a, m); s2a += __shfl_xor(s2a, m);
        s1b += __shfl_xor(s1b, m); s2b += __shfl_xor(s2b, m);
      }
      if (lane == 0) {
        float mean = s1a * (1.f / HID);
        float var = (s2a - (float)HID * mean * mean) * (1.f / (float)(HID - 1));
        stats_lds[wv][0] = mean;
        stats_lds[wv][1] = sqrtf(fmaxf(var, 0.f)) + EPS;
        mean = s1b * (1.f / HID);
        var = (s2b - (float)HID * mean * mean) * (1.f / (float)(HID - 1));
        stats_lds[4 + wv][0] = mean;
        stats_lds[4 + wv][1] = sqrtf(fmaxf(var, 0.f)) + EPS;
      }
    }
    __syncthreads();

    // ---- LN + relu ----
    if (doA) {
      float m0 = stats_lds[0][0], r0 = 1.f / stats_lds[0][1];
      float m1 = stats_lds[1][0], r1 = 1.f / stats_lds[1][1];
      float m2 = stats_lds[2][0], r2 = 1.f / stats_lds[2][1];
      float m3 = stats_lds[3][0], r3 = 1.f / stats_lds[3][1];
      #pragma unroll
      for (int j = 0; j < 4; ++j) {
        const int kk = tid + 256 * j;
        float h0 = fmaxf(ga[j] * (a2_lds[0 * HID + kk] - m0) * r0 + ba[j], 0.f);
        float h1 = fmaxf(ga[j] * (a2_lds[1 * HID + kk] - m1) * r1 + ba[j], 0.f);
        float h2 = fmaxf(ga[j] * (a2_lds[2 * HID + kk] - m2) * r2 + ba[j], 0.f);
        float h3 = fmaxf(ga[j] * (a2_lds[3 * HID + kk] - m3) * r3 + ba[j], 0.f);
        *(float4*)&h_a_lds[kk * 4] = make_float4(h0, h1, h2, h3);
      }
    }
    if (doB) {
      float m0 = stats_lds[4][0], r0 = 1.f / stats_lds[4][1];
      float m1 = stats_lds[5][0], r1 = 1.f / stats_lds[5][1];
      float m2 = stats_lds[6][0], r2 = 1.f / stats_lds[6][1];
      float m3 = stats_lds[7][0], r3 = 1.f / stats_lds[7][1];
      #pragma unroll
      for (int j = 0; j < 4; ++j) {
        const int kk = tid + 256 * j;
        float h0 = fmaxf(gb[j] * (a2_lds[4 * HID + kk] - m0) * r0 + bbq[j], 0.f);
        float h1 = fmaxf(gb[j] * (a2_lds[5 * HID + kk] - m1) * r1 + bbq[j], 0.f);
        float h2 = fmaxf(gb[j] * (a2_lds[6 * HID + kk] - m2) * r2 + bbq[j], 0.f);
        float h3 = fmaxf(gb[j] * (a2_lds[7 * HID + kk] - m3) * r3 + bbq[j], 0.f);
        *(float4*)&h_b_lds[kk * 4] = make_float4(h0, h1, h2, h3);
        if (c == 0) {
          const size_t hb0 = ((size_t)(k - 1) * BATCH + g * BPG) * HID + kk;
          h_all[hb0 + 0 * HID] = h0;
          h_all[hb0 + 1 * HID] = h1;
          h_all[hb0 + 2 * HID] = h2;
          h_all[hb0 + 3 * HID] = h3;
        }
      }
    }
    __syncthreads();
  }
}

// ---------------- softmax + loss/err per row (float2 loads) ----------------
__global__ __launch_bounds__(256) void softmax_loss(
    float* __restrict__ out, const int* __restrict__ lab, float* __restrict__ acc) {
  __shared__ float rowbuf[NCLS];
  __shared__ float rv[4]; __shared__ int ri[4]; __shared__ float rs[4];
  __shared__ float shv[2];
  __shared__ int shidx;
  const int m = blockIdx.x;
  float* row = out + (size_t)m * NCLS;
  const int tid = threadIdx.x;
  const int lane = tid & 63, wid = tid >> 6;

  float vmax = -1e30f; int vidx = 0x7fffffff;
  for (int c2 = tid; c2 < NCLS / 2; c2 += 256) {
    float2 v = *(const float2*)(row + 2 * c2);
    rowbuf[2 * c2] = v.x; rowbuf[2 * c2 + 1] = v.y;
    if (v.x > vmax) { vmax = v.x; vidx = 2 * c2; }
    if (v.y > vmax) { vmax = v.y; vidx = (v.x > v.y) ? vidx : 2 * c2 + 1; }
  }
  #pragma unroll
  for (int off = 32; off; off >>= 1) {
    float ov = __shfl_down(vmax, off);
    int oi = __shfl_down(vidx, off);
    if (ov > vmax || (ov == vmax && oi < vidx)) { vmax = ov; vidx = oi; }
  }
  if (lane == 0) { rv[wid] = vmax; ri[wid] = vidx; }
  __syncthreads();
  if (tid == 0) {
    float bm = rv[0]; int bi = ri[0];
    for (int w = 1; w < 4; ++w)
      if (rv[w] > bm || (rv[w] == bm && ri[w] < bi)) { bm = rv[w]; bi = ri[w]; }
    shv[0] = bm; shidx = bi;
  }
  __syncthreads();
  float gmax = shv[0];
  float s = 0.f;
  for (int c = tid; c < NCLS; c += 256) s += expf(rowbuf[c] - gmax);
  #pragma unroll
  for (int off = 32; off; off >>= 1) s += __shfl_down(s, off);
  if (lane == 0) rs[wid] = s;
  __syncthreads();
  if (tid == 0) shv[1] = rs[0] + rs[1] + rs[2] + rs[3];
  __syncthreads();
  float lse = logf(shv[1]);
  for (int c2 = tid; c2 < NCLS / 2; c2 += 256) {
    float2 v;
    v.x = rowbuf[2 * c2] - gmax - lse;
    v.y = rowbuf[2 * c2 + 1] - gmax - lse;
    *(float2*)(row + 2 * c2) = v;
  }
  if (tid == 0) {
    int lb = lab[m];
    float nll = -(rowbuf[lb] - gmax - lse);
    atomicAdd(acc + 0, nll);
    atomicAdd(acc + 1, (shidx != lb) ? 1.f : 0.f);
  }
}

__global__ void init_acc(float* acc) { acc[threadIdx.x] = 0.f; }

__global__ void finalize_out(const float* __restrict__ acc, float* __restrict__ out) {
  out[0] = acc[0] * (1.f / (float)MROWS);
  out[1] = acc[1] * (1.f / (float)MROWS);
}

extern "C" void kernel_launch(void* const* d_in, const int* in_sizes, int n_in,
                              void* d_out, int out_size, void* d_ws, size_t ws_size,
                              hipStream_t stream) {
  const float* x     = (const float*)d_in[0];
  const int*   lab   = (const int*)d_in[1];
  const float* wx0_w = (const float*)d_in[3];
  const float* wx0_b = (const float*)d_in[4];
  const float* wx_w  = (const float*)d_in[5];
  const float* wx_b  = (const float*)d_in[6];
  const float* uh_w  = (const float*)d_in[7];
  const float* ln_g  = (const float*)d_in[8];
  const float* ln_b  = (const float*)d_in[9];
  const float* fco_w = (const float*)d_in[10];
  const float* fco_b = (const float*)d_in[11];
  float* out = (float*)d_out;

  float* wsf = (float*)d_ws;
  size_t off = 0;
  auto carve = [&](size_t n) { float* p = wsf + off; off += (n + 63) & ~(size_t)63; return p; };
  float* wxbuf = carve((size_t)MROWS * HID);                    // 50 MB
  float* h_all = carve((size_t)MROWS * HID);                    // 50 MB
  float* pre   = carve((size_t)MROWS * HID);                    // 50 MB
  float* a_pub = carve((size_t)2 * NG * 2 * BPG * HID);         // 512 KB
  int*   prog  = (int*)carve((size_t)2 * NG * CPG2 * SLOTP);    // 32 KB (2 pairs)
  float* acc   = carve(64);

  (void)hipMemsetAsync(prog, 0, (size_t)2 * NG * CPG2 * SLOTP * sizeof(int), stream);
  init_acc<<<1, 2, 0, stream>>>(acc);

  const size_t HH = (size_t)HID * HID;

  // ---- pair 1: layers 0 (a) + 1 (b) ----
  gemm_mfma<3><<<dim3(HID / 128, MROWS / 128), 256, 0, stream>>>(
      x, wx0_w, wx0_b, wxbuf, MROWS, HID, 440);
  scan_pair<<<dim3(NG * CPG2), 256, 0, stream>>>(
      wxbuf, uh_w + 0 * HH, uh_w + 1 * HH, wx_w + 0 * HH, wx_b + 0 * HID,
      h_all, pre /*unused: skip*/, pre, a_pub, prog,
      ln_g + 0 * HID, ln_b + 0 * HID, ln_g + 1 * HID, ln_b + 1 * HID, 1);

  // ---- pair 2: layers 2 (a) + 3 (b) ----
  gemm_mfma<3><<<dim3(HID / 128, MROWS / 128), 256, 0, stream>>>(
      h_all, wx_w + 1 * HH, wx_b + 1 * HID, wxbuf, MROWS, HID, HID);
  scan_pair<<<dim3(NG * CPG2), 256, 0, stream>>>(
      wxbuf, uh_w + 2 * HH, uh_w + 3 * HH, wx_w + 2 * HH, wx_b + 2 * HID,
      h_all, pre /*reads pre_1*/, pre, a_pub, prog + (size_t)NG * CPG2 * SLOTP,
      ln_g + 2 * HID, ln_b + 2 * HID, ln_g + 3 * HID, ln_b + 3 * HID, 0);

  gemm_mfma<1><<<dim3((NCLS + 127) / 128, MROWS / 128), 256, 0, stream>>>(
      h_all, fco_w, fco_b, out + 2, MROWS, NCLS, HID);
  softmax_loss<<<MROWS, 256, 0, stream>>>(out + 2, lab, acc);
  finalize_out<<<1, 1, 0, stream>>>(acc, out);
}

// Round 15
// 10046.294 us; speedup vs baseline: 2.9655x; 2.9655x over previous
//
#include <hip/hip_runtime.h>
#include <math.h>

#define T_STEPS 400
#define BATCH   32
#define HID     1024
#define MROWS   (T_STEPS * BATCH)   // 12800
#define NCLS    3500
#define NG      8                    // batch groups
#define BPG     4                    // batch rows per group
#define CPG     32                   // blocks (column slices) per group
#define JS      32                   // columns per block
#define EPS     1e-6f
#define SLOTP   8                    // ints per progress slot (32B padding)

typedef __attribute__((ext_vector_type(8))) short short8v;   // 8 bf16 (4 VGPR)
typedef __attribute__((ext_vector_type(4))) float f32x4;

__device__ __forceinline__ unsigned short bf16_rne(float x) {
  unsigned u = __builtin_bit_cast(unsigned, x);
  unsigned r = u + 0x7FFFu + ((u >> 16) & 1u);
  return (unsigned short)(r >> 16);
}

// stage a 128x32 fp32 tile into hi/lo bf16 LDS tiles (chunk-XOR swizzled).
__device__ __forceinline__ void stage_tile(
    const float* __restrict__ src, int rowlim, int row0, int ld,
    int k0, int K, unsigned short* hi, unsigned short* lo, int tid) {
  #pragma unroll
  for (int it = 0; it < 2; ++it) {
    const int task = tid + 256 * it;          // 512 tasks: 128 rows x 4 chunks
    const int r = task >> 2, q = task & 3;
    const int gr = row0 + r;
    const bool rok = gr < rowlim;
    const float* p = src + (size_t)gr * ld + k0 + q * 8;
    float x[8];
    if (rok && (k0 + 32 <= K)) {
      float4 v0 = *(const float4*)p;
      float4 v1 = *(const float4*)(p + 4);
      x[0] = v0.x; x[1] = v0.y; x[2] = v0.z; x[3] = v0.w;
      x[4] = v1.x; x[5] = v1.y; x[6] = v1.z; x[7] = v1.w;
    } else {
      #pragma unroll
      for (int j = 0; j < 8; ++j)
        x[j] = (rok && (k0 + q * 8 + j) < K) ? p[j] : 0.f;
    }
    unsigned hp[4], lp[4];
    #pragma unroll
    for (int j = 0; j < 4; ++j) {
      unsigned short h0 = bf16_rne(x[2 * j]), h1 = bf16_rne(x[2 * j + 1]);
      float f0 = __builtin_bit_cast(float, (unsigned)h0 << 16);
      float f1 = __builtin_bit_cast(float, (unsigned)h1 << 16);
      unsigned short l0 = bf16_rne(x[2 * j] - f0), l1 = bf16_rne(x[2 * j + 1] - f1);
      hp[j] = (unsigned)h0 | ((unsigned)h1 << 16);
      lp[j] = (unsigned)l0 | ((unsigned)l1 << 16);
    }
    const int idx = (r * 4 + (q ^ (r & 3))) * 8;   // 16B-chunk swizzle
    *(uint4*)&hi[idx] = make_uint4(hp[0], hp[1], hp[2], hp[3]);
    *(uint4*)&lo[idx] = make_uint4(lp[0], lp[1], lp[2], lp[3]);
  }
}

// ---------------- MFMA GEMM: C[M][N] = A[M][K] @ W[N][K]^T + bias[N] ----------------
template <int NPASS>
__global__ __launch_bounds__(256) void gemm_mfma(
    const float* __restrict__ A, const float* __restrict__ W,
    const float* __restrict__ bias, float* __restrict__ C,
    int M, int N, int K) {
  __shared__ unsigned short Ah[128 * 32], Al[128 * 32];
  __shared__ unsigned short Bh[128 * 32], Bl[128 * 32];
  const int tid = threadIdx.x;
  const int m0 = blockIdx.y * 128, n0 = blockIdx.x * 128;
  const int w = tid >> 6, lane = tid & 63;
  const int rlow = lane & 15, ksel = lane >> 4;

  f32x4 acc[8][2];
  #pragma unroll
  for (int i = 0; i < 8; ++i) {
    acc[i][0] = (f32x4)(0.f);
    acc[i][1] = (f32x4)(0.f);
  }

  for (int k0 = 0; k0 < K; k0 += 32) {
    __syncthreads();
    stage_tile(A, M, m0, K, k0, K, Ah, Al, tid);
    stage_tile(W, N, n0, K, k0, K, Bh, Bl, tid);
    __syncthreads();

    short8v wh[2], wl[2];
    #pragma unroll
    for (int nf = 0; nf < 2; ++nf) {
      const int rn = w * 32 + nf * 16 + rlow;
      const int idx = (rn * 4 + (ksel ^ (rn & 3))) * 8;
      wh[nf] = *(const short8v*)&Bh[idx];
      if (NPASS == 3) wl[nf] = *(const short8v*)&Bl[idx];
    }
    #pragma unroll
    for (int i = 0; i < 8; ++i) {
      const int ra = i * 16 + rlow;
      const int idx = (ra * 4 + (ksel ^ (ra & 3))) * 8;
      short8v ah = *(const short8v*)&Ah[idx];
      if (NPASS == 3) {
        short8v al = *(const short8v*)&Al[idx];
        acc[i][0] = __builtin_amdgcn_mfma_f32_16x16x32_bf16(ah, wh[0], acc[i][0], 0, 0, 0);
        acc[i][0] = __builtin_amdgcn_mfma_f32_16x16x32_bf16(al, wh[0], acc[i][0], 0, 0, 0);
        acc[i][0] = __builtin_amdgcn_mfma_f32_16x16x32_bf16(ah, wl[0], acc[i][0], 0, 0, 0);
        acc[i][1] = __builtin_amdgcn_mfma_f32_16x16x32_bf16(ah, wh[1], acc[i][1], 0, 0, 0);
        acc[i][1] = __builtin_amdgcn_mfma_f32_16x16x32_bf16(al, wh[1], acc[i][1], 0, 0, 0);
        acc[i][1] = __builtin_amdgcn_mfma_f32_16x16x32_bf16(ah, wl[1], acc[i][1], 0, 0, 0);
      } else {
        acc[i][0] = __builtin_amdgcn_mfma_f32_16x16x32_bf16(ah, wh[0], acc[i][0], 0, 0, 0);
        acc[i][1] = __builtin_amdgcn_mfma_f32_16x16x32_bf16(ah, wh[1], acc[i][1], 0, 0, 0);
      }
    }
  }

  int col[2]; float bb[2]; bool cok[2];
  #pragma unroll
  for (int nf = 0; nf < 2; ++nf) {
    col[nf] = n0 + w * 32 + nf * 16 + rlow;
    cok[nf] = col[nf] < N;
    bb[nf] = cok[nf] ? bias[col[nf]] : 0.f;
  }
  #pragma unroll
  for (int i = 0; i < 8; ++i) {
    const int row = m0 + i * 16 + ksel * 4;
    #pragma unroll
    for (int nf = 0; nf < 2; ++nf) {
      if (cok[nf]) {
        float* cp = C + (size_t)row * N + col[nf];
        cp[0 * N] = acc[i][nf][0] + bb[nf];
        cp[1 * N] = acc[i][nf][1] + bb[nf];
        cp[2 * N] = acc[i][nf][2] + bb[nf];
        cp[3 * N] = acc[i][nf][3] + bb[nf];
      }
    }
  }
}

// ---------------- transpose 1024x1024: out[k][j] = in[j][k] ----------------
__global__ void transpose1024(const float* __restrict__ in, float* __restrict__ out) {
  __shared__ float tile[32][33];
  const int bx = blockIdx.x * 32, by = blockIdx.y * 32;
  const int tx = threadIdx.x, ty = threadIdx.y;  // 32 x 8
  #pragma unroll
  for (int i = 0; i < 32; i += 8)
    tile[ty + i][tx] = in[(size_t)(by + ty + i) * HID + bx + tx];
  __syncthreads();
  #pragma unroll
  for (int i = 0; i < 32; i += 8)
    out[(size_t)(bx + ty + i) * HID + by + tx] = tile[tx][ty + i];
}

// ---------------- scan: round-13 structure + 64-bit packed publish/readback ----------------
// Publish: 64 threads store float2 pairs as one 64-bit relaxed agent atomic (128->64 stores).
// Readback: 8 x 64-bit loads/thread (16->8), fused with stats accumulation.
__global__ __launch_bounds__(256, 1) void scan_layer(
    const float* __restrict__ wx, const float* __restrict__ uhT,
    float* __restrict__ h_all, float* __restrict__ pre_all,
    float* __restrict__ a_pub,        // [2][NG][BPG][HID], 8B-aligned
    int* __restrict__ prog,           // [NG][CPG][SLOTP]
    const float* __restrict__ gamma, const float* __restrict__ beta,
    int skip_sub) {
  const int tid  = threadIdx.x;
  const int g    = blockIdx.x >> 5;
  const int c    = blockIdx.x & 31;
  const int lane = tid & 63;
  const int wv   = tid >> 6;          // wave 0..3
  const int jw   = tid & 3;
  const int ks   = tid >> 2;          // 0..63
  const int col0 = c * JS + jw * 8;

  int* prog_g = prog + (size_t)g * CPG * SLOTP;

  __shared__ float h_lds[HID * BPG];      // flat [k*4+b], 16KB
  __shared__ float a_lds[BPG * HID];      // flat [b*1024+k], 16KB
  __shared__ float partial[4][BPG][JS];   // per-wave partials, 2KB
  __shared__ float stats_lds[BPG][2];
  __shared__ float g_lds[HID], be_lds[HID];

  for (int k = tid; k < HID; k += 256) { g_lds[k] = gamma[k]; be_lds[k] = beta[k]; }

  // persistent Uh slice in registers: rows ks+64i, cols col0..col0+7
  float4 u0[16], u1[16];
  #pragma unroll
  for (int i = 0; i < 16; ++i) {
    const float* p = uhT + (size_t)(ks + 64 * i) * HID + col0;
    u0[i] = *(const float4*)p;
    u1[i] = *(const float4*)(p + 4);
  }
  __syncthreads();

  for (int t = 0; t < T_STEPS; ++t) {
    const int par = t & 1;
    float* apub_t = a_pub + ((size_t)par * NG + g) * (BPG * HID);
    unsigned long long* ap64 = (unsigned long long*)apub_t;

    // issue wx / pre loads early (independent of h) — float2 per publisher thread
    float2 wx2 = make_float2(0.f, 0.f), pre2 = make_float2(0.f, 0.f);
    size_t gidx = 0;
    if (tid < 64) {
      const int b = tid >> 4, j2 = tid & 15;
      gidx = ((size_t)t * BATCH + g * BPG + b) * HID + c * JS + 2 * j2;
      wx2 = *(const float2*)&wx[gidx];
      if (!skip_sub) pre2 = *(const float2*)&pre_all[gidx];
    }

    if (t > 0) {
      float pacc[4][8];
      #pragma unroll
      for (int b = 0; b < 4; ++b)
        #pragma unroll
        for (int q = 0; q < 8; ++q) pacc[b][q] = 0.f;
      #pragma unroll
      for (int i = 0; i < 16; ++i) {
        float4 h4 = *(const float4*)&h_lds[(ks + 64 * i) * 4];  // 2-way: free
        #pragma unroll
        for (int b = 0; b < 4; ++b) {
          float hb = ((const float*)&h4)[b];
          pacc[b][0] += hb * u0[i].x; pacc[b][1] += hb * u0[i].y;
          pacc[b][2] += hb * u0[i].z; pacc[b][3] += hb * u0[i].w;
          pacc[b][4] += hb * u1[i].x; pacc[b][5] += hb * u1[i].y;
          pacc[b][6] += hb * u1[i].z; pacc[b][7] += hb * u1[i].w;
        }
      }
      // reduce 16 k-strips within wave (lane bits 2..5)
      #pragma unroll
      for (int b = 0; b < 4; ++b)
        #pragma unroll
        for (int q = 0; q < 8; ++q) {
          float v = pacc[b][q];
          v += __shfl_xor(v, 4);
          v += __shfl_xor(v, 8);
          v += __shfl_xor(v, 16);
          v += __shfl_xor(v, 32);
          pacc[b][q] = v;
        }
      if ((lane >> 2) == 0) {   // lanes 0..3, one per jw
        #pragma unroll
        for (int b = 0; b < 4; ++b) {
          *(float4*)&partial[wv][b][jw * 8]     = *(const float4*)&pacc[b][0];
          *(float4*)&partial[wv][b][jw * 8 + 4] = *(const float4*)&pacc[b][4];
        }
      }
    }
    __syncthreads();

    // finalize a-slice; publish float2 pairs as single 64-bit relaxed atomics
    if (tid < 64) {
      const int b = tid >> 4, j2 = tid & 15;
      float red0 = 0.f, red1 = 0.f;
      if (t > 0) {
        red0 = partial[0][b][2 * j2] + partial[1][b][2 * j2]
             + partial[2][b][2 * j2] + partial[3][b][2 * j2];
        red1 = partial[0][b][2 * j2 + 1] + partial[1][b][2 * j2 + 1]
             + partial[2][b][2 * j2 + 1] + partial[3][b][2 * j2 + 1];
      }
      float at0v = wx2.x + red0, at1v = wx2.y + red1;
      *(float2*)&pre_all[gidx] = make_float2(at0v, at1v);
      float2 av = make_float2(at0v - pre2.x, at1v - pre2.y);
      __hip_atomic_store(&ap64[((size_t)b * HID + c * JS) / 2 + j2],
                         __builtin_bit_cast(unsigned long long, av),
                         __ATOMIC_RELAXED, __HIP_MEMORY_SCOPE_AGENT);
    }
    // each thread drains its own outstanding stores before the barrier
    asm volatile("s_waitcnt vmcnt(0)" ::: "memory");
    __syncthreads();

    // announce: store step number to own slot (no RMW, no contention)
    if (tid == 0)
      __hip_atomic_store(&prog_g[c * SLOTP], t + 1,
                         __ATOMIC_RELAXED, __HIP_MEMORY_SCOPE_AGENT);
    // wave 0: each lane polls one of the 32 slots until all reached t+1
    if (wv == 0) {
      const int* p = &prog_g[(lane & 31) * SLOTP];
      bool first = true;
      while (true) {
        int v = __hip_atomic_load(p, __ATOMIC_RELAXED, __HIP_MEMORY_SCOPE_AGENT);
        if (__all(v >= t + 1)) break;
        if (!first) __builtin_amdgcn_s_sleep(1);
        first = false;
      }
    }
    __syncthreads();

    // fused readback + stats: wave wv reads row wv as 8 x 64-bit pairs,
    // accumulates s1/s2 from registers, stages into a_lds.
    {
      float2 vals[8];
      float s1 = 0.f, s2 = 0.f;
      #pragma unroll
      for (int i = 0; i < 8; ++i) {
        unsigned long long pk = __hip_atomic_load(
            &ap64[(size_t)wv * (HID / 2) + i * 64 + lane],
            __ATOMIC_RELAXED, __HIP_MEMORY_SCOPE_AGENT);
        float2 v = __builtin_bit_cast(float2, pk);
        vals[i] = v;
        s1 += v.x + v.y;
        s2 += v.x * v.x + v.y * v.y;
      }
      #pragma unroll
      for (int i = 0; i < 8; ++i)
        *(float2*)&a_lds[wv * HID + i * 128 + lane * 2] = vals[i];
      #pragma unroll
      for (int m = 1; m <= 32; m <<= 1) { s1 += __shfl_xor(s1, m); s2 += __shfl_xor(s2, m); }
      if (lane == 0) {
        float mean = s1 * (1.f / HID);
        float var = (s2 - (float)HID * mean * mean) * (1.f / (float)(HID - 1));
        stats_lds[wv][0] = mean;
        stats_lds[wv][1] = sqrtf(fmaxf(var, 0.f)) + EPS;
      }
    }
    __syncthreads();

    // h = relu(LN(a)) for rows k = tid + 256*j; write h_lds[k*4+b] (2-way: free)
    {
      float mean0 = stats_lds[0][0], rd0 = 1.f / stats_lds[0][1];
      float mean1 = stats_lds[1][0], rd1 = 1.f / stats_lds[1][1];
      float mean2 = stats_lds[2][0], rd2 = 1.f / stats_lds[2][1];
      float mean3 = stats_lds[3][0], rd3 = 1.f / stats_lds[3][1];
      #pragma unroll
      for (int j = 0; j < 4; ++j) {
        const int k = tid + 256 * j;
        float gk = g_lds[k], bk = be_lds[k];
        float h0 = fmaxf(gk * (a_lds[0 * HID + k] - mean0) * rd0 + bk, 0.f);
        float h1 = fmaxf(gk * (a_lds[1 * HID + k] - mean1) * rd1 + bk, 0.f);
        float h2 = fmaxf(gk * (a_lds[2 * HID + k] - mean2) * rd2 + bk, 0.f);
        float h3 = fmaxf(gk * (a_lds[3 * HID + k] - mean3) * rd3 + bk, 0.f);
        *(float4*)&h_lds[k * 4] = make_float4(h0, h1, h2, h3);
        if (c == 0) {
          h_all[((size_t)t * BATCH + g * BPG + 0) * HID + k] = h0;
          h_all[((size_t)t * BATCH + g * BPG + 1) * HID + k] = h1;
          h_all[((size_t)t * BATCH + g * BPG + 2) * HID + k] = h2;
          h_all[((size_t)t * BATCH + g * BPG + 3) * HID + k] = h3;
        }
      }
    }
    __syncthreads();
  }
}

// ---------------- softmax + loss/err per row (float2 loads) ----------------
__global__ __launch_bounds__(256) void softmax_loss(
    float* __restrict__ out, const int* __restrict__ lab, float* __restrict__ acc) {
  __shared__ float rowbuf[NCLS];
  __shared__ float rv[4]; __shared__ int ri[4]; __shared__ float rs[4];
  __shared__ float shv[2];
  __shared__ int shidx;
  const int m = blockIdx.x;
  float* row = out + (size_t)m * NCLS;
  const int tid = threadIdx.x;
  const int lane = tid & 63, wid = tid >> 6;

  float vmax = -1e30f; int vidx = 0x7fffffff;
  for (int c2 = tid; c2 < NCLS / 2; c2 += 256) {
    float2 v = *(const float2*)(row + 2 * c2);
    rowbuf[2 * c2] = v.x; rowbuf[2 * c2 + 1] = v.y;
    if (v.x > vmax) { vmax = v.x; vidx = 2 * c2; }
    if (v.y > vmax) { vmax = v.y; vidx = (v.x > v.y) ? vidx : 2 * c2 + 1; }
  }
  #pragma unroll
  for (int off = 32; off; off >>= 1) {
    float ov = __shfl_down(vmax, off);
    int oi = __shfl_down(vidx, off);
    if (ov > vmax || (ov == vmax && oi < vidx)) { vmax = ov; vidx = oi; }
  }
  if (lane == 0) { rv[wid] = vmax; ri[wid] = vidx; }
  __syncthreads();
  if (tid == 0) {
    float bm = rv[0]; int bi = ri[0];
    for (int w = 1; w < 4; ++w)
      if (rv[w] > bm || (rv[w] == bm && ri[w] < bi)) { bm = rv[w]; bi = ri[w]; }
    shv[0] = bm; shidx = bi;
  }
  __syncthreads();
  float gmax = shv[0];
  float s = 0.f;
  for (int c = tid; c < NCLS; c += 256) s += expf(rowbuf[c] - gmax);
  #pragma unroll
  for (int off = 32; off; off >>= 1) s += __shfl_down(s, off);
  if (lane == 0) rs[wid] = s;
  __syncthreads();
  if (tid == 0) shv[1] = rs[0] + rs[1] + rs[2] + rs[3];
  __syncthreads();
  float lse = logf(shv[1]);
  for (int c2 = tid; c2 < NCLS / 2; c2 += 256) {
    float2 v;
    v.x = rowbuf[2 * c2] - gmax - lse;
    v.y = rowbuf[2 * c2 + 1] - gmax - lse;
    *(float2*)(row + 2 * c2) = v;
  }
  if (tid == 0) {
    int lb = lab[m];
    float nll = -(rowbuf[lb] - gmax - lse);
    atomicAdd(acc + 0, nll);
    atomicAdd(acc + 1, (shidx != lb) ? 1.f : 0.f);
  }
}

__global__ void init_acc(float* acc) { acc[threadIdx.x] = 0.f; }

__global__ void finalize_out(const float* __restrict__ acc, float* __restrict__ out) {
  out[0] = acc[0] * (1.f / (float)MROWS);
  out[1] = acc[1] * (1.f / (float)MROWS);
}

extern "C" void kernel_launch(void* const* d_in, const int* in_sizes, int n_in,
                              void* d_out, int out_size, void* d_ws, size_t ws_size,
                              hipStream_t stream) {
  const float* x     = (const float*)d_in[0];
  const int*   lab   = (const int*)d_in[1];
  const float* wx0_w = (const float*)d_in[3];
  const float* wx0_b = (const float*)d_in[4];
  const float* wx_w  = (const float*)d_in[5];
  const float* wx_b  = (const float*)d_in[6];
  const float* uh_w  = (const float*)d_in[7];
  const float* ln_g  = (const float*)d_in[8];
  const float* ln_b  = (const float*)d_in[9];
  const float* fco_w = (const float*)d_in[10];
  const float* fco_b = (const float*)d_in[11];
  float* out = (float*)d_out;

  float* wsf = (float*)d_ws;
  size_t off = 0;
  auto carve = [&](size_t n) { float* p = wsf + off; off += (n + 63) & ~(size_t)63; return p; };
  float* uhT   = carve((size_t)HID * HID);                 //  4 MB
  float* wxbuf = carve((size_t)MROWS * HID);               // 50 MB
  float* h_all = carve((size_t)MROWS * HID);               // 50 MB
  float* pre   = carve((size_t)MROWS * HID);               // 50 MB
  float* a_pub = carve((size_t)2 * NG * BPG * HID);        // 256 KB
  int*   prog  = (int*)carve((size_t)4 * NG * CPG * SLOTP); // 32 KB (4 layers)
  float* acc   = carve(64);

  (void)hipMemsetAsync(prog, 0, (size_t)4 * NG * CPG * SLOTP * sizeof(int), stream);
  init_acc<<<1, 2, 0, stream>>>(acc);

  for (int layer = 0; layer < 4; ++layer) {
    if (layer == 0) {
      gemm_mfma<3><<<dim3(HID / 128, MROWS / 128), 256, 0, stream>>>(
          x, wx0_w, wx0_b, wxbuf, MROWS, HID, 440);
    } else {
      gemm_mfma<3><<<dim3(HID / 128, MROWS / 128), 256, 0, stream>>>(
          h_all, wx_w + (size_t)(layer - 1) * HID * HID,
          wx_b + (size_t)(layer - 1) * HID, wxbuf, MROWS, HID, HID);
    }
    transpose1024<<<dim3(32, 32), dim3(32, 8), 0, stream>>>(
        uh_w + (size_t)layer * HID * HID, uhT);

    scan_layer<<<dim3(NG * CPG), 256, 0, stream>>>(
        wxbuf, uhT, h_all, pre, a_pub, prog + (size_t)layer * NG * CPG * SLOTP,
        ln_g + (size_t)layer * HID, ln_b + (size_t)layer * HID,
        (layer == 0) ? 1 : 0);
  }

  gemm_mfma<1><<<dim3((NCLS + 127) / 128, MROWS / 128), 256, 0, stream>>>(
      h_all, fco_w, fco_b, out + 2, MROWS, NCLS, HID);
  softmax_loss<<<MROWS, 256, 0, stream>>>(out + 2, lab, acc);
  finalize_out<<<1, 1, 0, stream>>>(acc, out);
}

// Round 16
// 9872.448 us; speedup vs baseline: 3.0177x; 1.0176x over previous
//
#include <hip/hip_runtime.h>
#include <math.h>

#define T_STEPS 400
#define BATCH   32
#define HID     1024
#define MROWS   (T_STEPS * BATCH)   // 12800
#define NCLS    3500
#define NG      8                    // batch groups
#define BPG     4                    // batch rows per group
#define CPG     32                   // blocks (column slices) per group
#define JS      32                   // columns per block
#define EPS     1e-6f
#define SLOTP   8                    // ints per progress slot (32B padding)

typedef __attribute__((ext_vector_type(8))) short short8v;   // 8 bf16 (4 VGPR)
typedef __attribute__((ext_vector_type(4))) float f32x4;

__device__ __forceinline__ unsigned short bf16_rne(float x) {
  unsigned u = __builtin_bit_cast(unsigned, x);
  unsigned r = u + 0x7FFFu + ((u >> 16) & 1u);
  return (unsigned short)(r >> 16);
}

// stage a 128x32 fp32 tile into hi/lo bf16 LDS tiles (chunk-XOR swizzled).
__device__ __forceinline__ void stage_tile(
    const float* __restrict__ src, int rowlim, int row0, int ld,
    int k0, int K, unsigned short* hi, unsigned short* lo, int tid) {
  #pragma unroll
  for (int it = 0; it < 2; ++it) {
    const int task = tid + 256 * it;          // 512 tasks: 128 rows x 4 chunks
    const int r = task >> 2, q = task & 3;
    const int gr = row0 + r;
    const bool rok = gr < rowlim;
    const float* p = src + (size_t)gr * ld + k0 + q * 8;
    float x[8];
    if (rok && (k0 + 32 <= K)) {
      float4 v0 = *(const float4*)p;
      float4 v1 = *(const float4*)(p + 4);
      x[0] = v0.x; x[1] = v0.y; x[2] = v0.z; x[3] = v0.w;
      x[4] = v1.x; x[5] = v1.y; x[6] = v1.z; x[7] = v1.w;
    } else {
      #pragma unroll
      for (int j = 0; j < 8; ++j)
        x[j] = (rok && (k0 + q * 8 + j) < K) ? p[j] : 0.f;
    }
    unsigned hp[4], lp[4];
    #pragma unroll
    for (int j = 0; j < 4; ++j) {
      unsigned short h0 = bf16_rne(x[2 * j]), h1 = bf16_rne(x[2 * j + 1]);
      float f0 = __builtin_bit_cast(float, (unsigned)h0 << 16);
      float f1 = __builtin_bit_cast(float, (unsigned)h1 << 16);
      unsigned short l0 = bf16_rne(x[2 * j] - f0), l1 = bf16_rne(x[2 * j + 1] - f1);
      hp[j] = (unsigned)h0 | ((unsigned)h1 << 16);
      lp[j] = (unsigned)l0 | ((unsigned)l1 << 16);
    }
    const int idx = (r * 4 + (q ^ (r & 3))) * 8;   // 16B-chunk swizzle
    *(uint4*)&hi[idx] = make_uint4(hp[0], hp[1], hp[2], hp[3]);
    *(uint4*)&lo[idx] = make_uint4(lp[0], lp[1], lp[2], lp[3]);
  }
}

// ---------------- MFMA GEMM: C[M][N] = A[M][K] @ W[N][K]^T + bias[N] ----------------
template <int NPASS>
__global__ __launch_bounds__(256) void gemm_mfma(
    const float* __restrict__ A, const float* __restrict__ W,
    const float* __restrict__ bias, float* __restrict__ C,
    int M, int N, int K) {
  __shared__ unsigned short Ah[128 * 32], Al[128 * 32];
  __shared__ unsigned short Bh[128 * 32], Bl[128 * 32];
  const int tid = threadIdx.x;
  const int m0 = blockIdx.y * 128, n0 = blockIdx.x * 128;
  const int w = tid >> 6, lane = tid & 63;
  const int rlow = lane & 15, ksel = lane >> 4;

  f32x4 acc[8][2];
  #pragma unroll
  for (int i = 0; i < 8; ++i) {
    acc[i][0] = (f32x4)(0.f);
    acc[i][1] = (f32x4)(0.f);
  }

  for (int k0 = 0; k0 < K; k0 += 32) {
    __syncthreads();
    stage_tile(A, M, m0, K, k0, K, Ah, Al, tid);
    stage_tile(W, N, n0, K, k0, K, Bh, Bl, tid);
    __syncthreads();

    short8v wh[2], wl[2];
    #pragma unroll
    for (int nf = 0; nf < 2; ++nf) {
      const int rn = w * 32 + nf * 16 + rlow;
      const int idx = (rn * 4 + (ksel ^ (rn & 3))) * 8;
      wh[nf] = *(const short8v*)&Bh[idx];
      if (NPASS == 3) wl[nf] = *(const short8v*)&Bl[idx];
    }
    #pragma unroll
    for (int i = 0; i < 8; ++i) {
      const int ra = i * 16 + rlow;
      const int idx = (ra * 4 + (ksel ^ (ra & 3))) * 8;
      short8v ah = *(const short8v*)&Ah[idx];
      if (NPASS == 3) {
        short8v al = *(const short8v*)&Al[idx];
        acc[i][0] = __builtin_amdgcn_mfma_f32_16x16x32_bf16(ah, wh[0], acc[i][0], 0, 0, 0);
        acc[i][0] = __builtin_amdgcn_mfma_f32_16x16x32_bf16(al, wh[0], acc[i][0], 0, 0, 0);
        acc[i][0] = __builtin_amdgcn_mfma_f32_16x16x32_bf16(ah, wl[0], acc[i][0], 0, 0, 0);
        acc[i][1] = __builtin_amdgcn_mfma_f32_16x16x32_bf16(ah, wh[1], acc[i][1], 0, 0, 0);
        acc[i][1] = __builtin_amdgcn_mfma_f32_16x16x32_bf16(al, wh[1], acc[i][1], 0, 0, 0);
        acc[i][1] = __builtin_amdgcn_mfma_f32_16x16x32_bf16(ah, wl[1], acc[i][1], 0, 0, 0);
      } else {
        acc[i][0] = __builtin_amdgcn_mfma_f32_16x16x32_bf16(ah, wh[0], acc[i][0], 0, 0, 0);
        acc[i][1] = __builtin_amdgcn_mfma_f32_16x16x32_bf16(ah, wh[1], acc[i][1], 0, 0, 0);
      }
    }
  }

  int col[2]; float bb[2]; bool cok[2];
  #pragma unroll
  for (int nf = 0; nf < 2; ++nf) {
    col[nf] = n0 + w * 32 + nf * 16 + rlow;
    cok[nf] = col[nf] < N;
    bb[nf] = cok[nf] ? bias[col[nf]] : 0.f;
  }
  #pragma unroll
  for (int i = 0; i < 8; ++i) {
    const int row = m0 + i * 16 + ksel * 4;
    #pragma unroll
    for (int nf = 0; nf < 2; ++nf) {
      if (cok[nf]) {
        float* cp = C + (size_t)row * N + col[nf];
        cp[0 * N] = acc[i][nf][0] + bb[nf];
        cp[1 * N] = acc[i][nf][1] + bb[nf];
        cp[2 * N] = acc[i][nf][2] + bb[nf];
        cp[3 * N] = acc[i][nf][3] + bb[nf];
      }
    }
  }
}

// ---------------- transpose 1024x1024: out[k][j] = in[j][k] ----------------
__global__ void transpose1024(const float* __restrict__ in, float* __restrict__ out) {
  __shared__ float tile[32][33];
  const int bx = blockIdx.x * 32, by = blockIdx.y * 32;
  const int tx = threadIdx.x, ty = threadIdx.y;  // 32 x 8
  #pragma unroll
  for (int i = 0; i < 32; i += 8)
    tile[ty + i][tx] = in[(size_t)(by + ty + i) * HID + bx + tx];
  __syncthreads();
  #pragma unroll
  for (int i = 0; i < 32; i += 8)
    out[(size_t)(bx + ty + i) * HID + by + tx] = tile[tx][ty + i];
}

// ---------------- scan: round-13 best (fused readback/stats, scalar publish) ----------------
__global__ __launch_bounds__(256, 1) void scan_layer(
    const float* __restrict__ wx, const float* __restrict__ uhT,
    float* __restrict__ h_all, float* __restrict__ pre_all,
    float* __restrict__ a_pub,        // [2][NG][BPG][HID]
    int* __restrict__ prog,           // [NG][CPG][SLOTP]
    const float* __restrict__ gamma, const float* __restrict__ beta,
    int skip_sub) {
  const int tid  = threadIdx.x;
  const int g    = blockIdx.x >> 5;
  const int c    = blockIdx.x & 31;
  const int lane = tid & 63;
  const int wv   = tid >> 6;          // wave 0..3
  const int jw   = tid & 3;
  const int ks   = tid >> 2;          // 0..63
  const int col0 = c * JS + jw * 8;

  int* prog_g = prog + (size_t)g * CPG * SLOTP;

  __shared__ float h_lds[HID * BPG];      // flat [k*4+b], 16KB
  __shared__ float a_lds[BPG * HID];      // flat [b*1024+k], 16KB
  __shared__ float partial[4][BPG][JS];   // per-wave partials, 2KB
  __shared__ float stats_lds[BPG][2];
  __shared__ float g_lds[HID], be_lds[HID];

  for (int k = tid; k < HID; k += 256) { g_lds[k] = gamma[k]; be_lds[k] = beta[k]; }

  // persistent Uh slice in registers: rows ks+64i, cols col0..col0+7
  float4 u0[16], u1[16];
  #pragma unroll
  for (int i = 0; i < 16; ++i) {
    const float* p = uhT + (size_t)(ks + 64 * i) * HID + col0;
    u0[i] = *(const float4*)p;
    u1[i] = *(const float4*)(p + 4);
  }
  __syncthreads();

  for (int t = 0; t < T_STEPS; ++t) {
    const int par = t & 1;
    float* apub_t = a_pub + ((size_t)par * NG + g) * (BPG * HID);

    // issue wx / pre loads early (independent of h)
    float at0 = 0.f, pre_old = 0.f;
    size_t gidx = 0;
    if (tid < 128) {
      const int b = tid >> 5, j = tid & 31;
      gidx = ((size_t)t * BATCH + g * BPG + b) * HID + c * JS + j;
      at0 = wx[gidx];
      pre_old = skip_sub ? 0.f : pre_all[gidx];
    }

    if (t > 0) {
      float pacc[4][8];
      #pragma unroll
      for (int b = 0; b < 4; ++b)
        #pragma unroll
        for (int q = 0; q < 8; ++q) pacc[b][q] = 0.f;
      #pragma unroll
      for (int i = 0; i < 16; ++i) {
        float4 h4 = *(const float4*)&h_lds[(ks + 64 * i) * 4];  // 2-way: free
        #pragma unroll
        for (int b = 0; b < 4; ++b) {
          float hb = ((const float*)&h4)[b];
          pacc[b][0] += hb * u0[i].x; pacc[b][1] += hb * u0[i].y;
          pacc[b][2] += hb * u0[i].z; pacc[b][3] += hb * u0[i].w;
          pacc[b][4] += hb * u1[i].x; pacc[b][5] += hb * u1[i].y;
          pacc[b][6] += hb * u1[i].z; pacc[b][7] += hb * u1[i].w;
        }
      }
      // reduce 16 k-strips within wave (lane bits 2..5)
      #pragma unroll
      for (int b = 0; b < 4; ++b)
        #pragma unroll
        for (int q = 0; q < 8; ++q) {
          float v = pacc[b][q];
          v += __shfl_xor(v, 4);
          v += __shfl_xor(v, 8);
          v += __shfl_xor(v, 16);
          v += __shfl_xor(v, 32);
          pacc[b][q] = v;
        }
      if ((lane >> 2) == 0) {   // lanes 0..3, one per jw
        #pragma unroll
        for (int b = 0; b < 4; ++b) {
          *(float4*)&partial[wv][b][jw * 8]     = *(const float4*)&pacc[b][0];
          *(float4*)&partial[wv][b][jw * 8 + 4] = *(const float4*)&pacc[b][4];
        }
      }
    }
    __syncthreads();

    // finalize a-slice; publish via IF-coherent relaxed atomic stores (no fence)
    if (tid < 128) {
      const int b = tid >> 5, j = tid & 31;
      float red = 0.f;
      if (t > 0)
        red = partial[0][b][j] + partial[1][b][j] + partial[2][b][j] + partial[3][b][j];
      float at = at0 + red;
      pre_all[gidx] = at;
      __hip_atomic_store(&apub_t[(size_t)b * HID + c * JS + j], at - pre_old,
                         __ATOMIC_RELAXED, __HIP_MEMORY_SCOPE_AGENT);
    }
    // each thread drains its own outstanding stores before the barrier
    asm volatile("s_waitcnt vmcnt(0)" ::: "memory");
    __syncthreads();

    // announce: store step number to own slot (no RMW, no contention)
    if (tid == 0)
      __hip_atomic_store(&prog_g[c * SLOTP], t + 1,
                         __ATOMIC_RELAXED, __HIP_MEMORY_SCOPE_AGENT);
    // wave 0: each lane polls one of the 32 slots until all reached t+1
    if (wv == 0) {
      const int* p = &prog_g[(lane & 31) * SLOTP];
      bool first = true;
      while (true) {
        int v = __hip_atomic_load(p, __ATOMIC_RELAXED, __HIP_MEMORY_SCOPE_AGENT);
        if (__all(v >= t + 1)) break;
        if (!first) __builtin_amdgcn_s_sleep(1);
        first = false;
      }
    }
    __syncthreads();

    // fused readback + stats: thread (wv,lane) loads row wv entries i*64+lane,
    // accumulates s1/s2 from registers, writes same values to a_lds.
    {
      float vals[16];
      float s1 = 0.f, s2 = 0.f;
      #pragma unroll
      for (int i = 0; i < 16; ++i) {
        float v = __hip_atomic_load(&apub_t[(size_t)wv * HID + i * 64 + lane],
                                    __ATOMIC_RELAXED, __HIP_MEMORY_SCOPE_AGENT);
        vals[i] = v;
        s1 += v; s2 += v * v;
      }
      #pragma unroll
      for (int i = 0; i < 16; ++i)
        a_lds[wv * HID + i * 64 + lane] = vals[i];
      #pragma unroll
      for (int m = 1; m <= 32; m <<= 1) { s1 += __shfl_xor(s1, m); s2 += __shfl_xor(s2, m); }
      if (lane == 0) {
        float mean = s1 * (1.f / HID);
        float var = (s2 - (float)HID * mean * mean) * (1.f / (float)(HID - 1));
        stats_lds[wv][0] = mean;
        stats_lds[wv][1] = sqrtf(fmaxf(var, 0.f)) + EPS;
      }
    }
    __syncthreads();

    // h = relu(LN(a)) for rows k = tid + 256*j; write h_lds[k*4+b] (2-way: free)
    {
      float mean0 = stats_lds[0][0], rd0 = 1.f / stats_lds[0][1];
      float mean1 = stats_lds[1][0], rd1 = 1.f / stats_lds[1][1];
      float mean2 = stats_lds[2][0], rd2 = 1.f / stats_lds[2][1];
      float mean3 = stats_lds[3][0], rd3 = 1.f / stats_lds[3][1];
      #pragma unroll
      for (int j = 0; j < 4; ++j) {
        const int k = tid + 256 * j;
        float gk = g_lds[k], bk = be_lds[k];
        float h0 = fmaxf(gk * (a_lds[0 * HID + k] - mean0) * rd0 + bk, 0.f);
        float h1 = fmaxf(gk * (a_lds[1 * HID + k] - mean1) * rd1 + bk, 0.f);
        float h2 = fmaxf(gk * (a_lds[2 * HID + k] - mean2) * rd2 + bk, 0.f);
        float h3 = fmaxf(gk * (a_lds[3 * HID + k] - mean3) * rd3 + bk, 0.f);
        *(float4*)&h_lds[k * 4] = make_float4(h0, h1, h2, h3);
        if (c == 0) {
          h_all[((size_t)t * BATCH + g * BPG + 0) * HID + k] = h0;
          h_all[((size_t)t * BATCH + g * BPG + 1) * HID + k] = h1;
          h_all[((size_t)t * BATCH + g * BPG + 2) * HID + k] = h2;
          h_all[((size_t)t * BATCH + g * BPG + 3) * HID + k] = h3;
        }
      }
    }
    __syncthreads();
  }
}

// ---------------- softmax + loss/err per row (float2 loads) ----------------
__global__ __launch_bounds__(256) void softmax_loss(
    float* __restrict__ out, const int* __restrict__ lab, float* __restrict__ acc) {
  __shared__ float rowbuf[NCLS];
  __shared__ float rv[4]; __shared__ int ri[4]; __shared__ float rs[4];
  __shared__ float shv[2];
  __shared__ int shidx;
  const int m = blockIdx.x;
  float* row = out + (size_t)m * NCLS;
  const int tid = threadIdx.x;
  const int lane = tid & 63, wid = tid >> 6;

  float vmax = -1e30f; int vidx = 0x7fffffff;
  for (int c2 = tid; c2 < NCLS / 2; c2 += 256) {
    float2 v = *(const float2*)(row + 2 * c2);
    rowbuf[2 * c2] = v.x; rowbuf[2 * c2 + 1] = v.y;
    if (v.x > vmax) { vmax = v.x; vidx = 2 * c2; }
    if (v.y > vmax) { vmax = v.y; vidx = (v.x > v.y) ? vidx : 2 * c2 + 1; }
  }
  #pragma unroll
  for (int off = 32; off; off >>= 1) {
    float ov = __shfl_down(vmax, off);
    int oi = __shfl_down(vidx, off);
    if (ov > vmax || (ov == vmax && oi < vidx)) { vmax = ov; vidx = oi; }
  }
  if (lane == 0) { rv[wid] = vmax; ri[wid] = vidx; }
  __syncthreads();
  if (tid == 0) {
    float bm = rv[0]; int bi = ri[0];
    for (int w = 1; w < 4; ++w)
      if (rv[w] > bm || (rv[w] == bm && ri[w] < bi)) { bm = rv[w]; bi = ri[w]; }
    shv[0] = bm; shidx = bi;
  }
  __syncthreads();
  float gmax = shv[0];
  float s = 0.f;
  for (int c = tid; c < NCLS; c += 256) s += expf(rowbuf[c] - gmax);
  #pragma unroll
  for (int off = 32; off; off >>= 1) s += __shfl_down(s, off);
  if (lane == 0) rs[wid] = s;
  __syncthreads();
  if (tid == 0) shv[1] = rs[0] + rs[1] + rs[2] + rs[3];
  __syncthreads();
  float lse = logf(shv[1]);
  for (int c2 = tid; c2 < NCLS / 2; c2 += 256) {
    float2 v;
    v.x = rowbuf[2 * c2] - gmax - lse;
    v.y = rowbuf[2 * c2 + 1] - gmax - lse;
    *(float2*)(row + 2 * c2) = v;
  }
  if (tid == 0) {
    int lb = lab[m];
    float nll = -(rowbuf[lb] - gmax - lse);
    atomicAdd(acc + 0, nll);
    atomicAdd(acc + 1, (shidx != lb) ? 1.f : 0.f);
  }
}

__global__ void init_acc(float* acc) { acc[threadIdx.x] = 0.f; }

__global__ void finalize_out(const float* __restrict__ acc, float* __restrict__ out) {
  out[0] = acc[0] * (1.f / (float)MROWS);
  out[1] = acc[1] * (1.f / (float)MROWS);
}

extern "C" void kernel_launch(void* const* d_in, const int* in_sizes, int n_in,
                              void* d_out, int out_size, void* d_ws, size_t ws_size,
                              hipStream_t stream) {
  const float* x     = (const float*)d_in[0];
  const int*   lab   = (const int*)d_in[1];
  const float* wx0_w = (const float*)d_in[3];
  const float* wx0_b = (const float*)d_in[4];
  const float* wx_w  = (const float*)d_in[5];
  const float* wx_b  = (const float*)d_in[6];
  const float* uh_w  = (const float*)d_in[7];
  const float* ln_g  = (const float*)d_in[8];
  const float* ln_b  = (const float*)d_in[9];
  const float* fco_w = (const float*)d_in[10];
  const float* fco_b = (const float*)d_in[11];
  float* out = (float*)d_out;

  float* wsf = (float*)d_ws;
  size_t off = 0;
  auto carve = [&](size_t n) { float* p = wsf + off; off += (n + 63) & ~(size_t)63; return p; };
  float* uhT   = carve((size_t)HID * HID);                 //  4 MB
  float* wxbuf = carve((size_t)MROWS * HID);               // 50 MB
  float* h_all = carve((size_t)MROWS * HID);               // 50 MB
  float* pre   = carve((size_t)MROWS * HID);               // 50 MB
  float* a_pub = carve((size_t)2 * NG * BPG * HID);        // 256 KB
  int*   prog  = (int*)carve((size_t)4 * NG * CPG * SLOTP); // 32 KB (4 layers)
  float* acc   = carve(64);

  (void)hipMemsetAsync(prog, 0, (size_t)4 * NG * CPG * SLOTP * sizeof(int), stream);
  init_acc<<<1, 2, 0, stream>>>(acc);

  for (int layer = 0; layer < 4; ++layer) {
    if (layer == 0) {
      gemm_mfma<3><<<dim3(HID / 128, MROWS / 128), 256, 0, stream>>>(
          x, wx0_w, wx0_b, wxbuf, MROWS, HID, 440);
    } else {
      gemm_mfma<3><<<dim3(HID / 128, MROWS / 128), 256, 0, stream>>>(
          h_all, wx_w + (size_t)(layer - 1) * HID * HID,
          wx_b + (size_t)(layer - 1) * HID, wxbuf, MROWS, HID, HID);
    }
    transpose1024<<<dim3(32, 32), dim3(32, 8), 0, stream>>>(
        uh_w + (size_t)layer * HID * HID, uhT);

    scan_layer<<<dim3(NG * CPG), 256, 0, stream>>>(
        wxbuf, uhT, h_all, pre, a_pub, prog + (size_t)layer * NG * CPG * SLOTP,
        ln_g + (size_t)layer * HID, ln_b + (size_t)layer * HID,
        (layer == 0) ? 1 : 0);
  }

  gemm_mfma<1><<<dim3((NCLS + 127) / 128, MROWS / 128), 256, 0, stream>>>(
      h_all, fco_w, fco_b, out + 2, MROWS, NCLS, HID);
  softmax_loss<<<MROWS, 256, 0, stream>>>(out + 2, lab, acc);
  finalize_out<<<1, 1, 0, stream>>>(acc, out);
}